// Round 1
// baseline (11932.549 us; speedup 1.0000x reference)
//
#include <hip/hip_runtime.h>
#include <math.h>

#define TT   96
#define SSS  128
#define DMM  512
#define DSS  256
#define BSS  512          // B*S tokens
#define NBLK 256
#define NTHR 512
#define DECAYF 0.6065306597126334f
#define SMEM_BYTES 69632

// ---------------- workspace layout (float offsets) ----------------
static constexpr size_t OFS_K     = 0;
static constexpr size_t SZ_KV     = (size_t)TT * BSS * DSS;        // 12582912
static constexpr size_t OFS_V     = OFS_K + SZ_KV;
static constexpr size_t OFS_XD    = OFS_V + SZ_KV;                 // x @ D^T
static constexpr size_t SZ_XD     = (size_t)TT * BSS * DMM;
static constexpr size_t OFS_H     = OFS_XD + SZ_XD;                // LIF1 spikes [BSS][DSS]
static constexpr size_t OFS_SV    = OFS_H  + (size_t)BSS * DSS;    // LIF1 vmem
static constexpr size_t OFS_OV    = OFS_SV + (size_t)BSS * DSS;    // LIF2 vmem [BSS][DMM]
static constexpr size_t OFS_ST    = OFS_OV + (size_t)BSS * DMM;    // h @ A^T
static constexpr size_t OFS_Q     = OFS_ST + (size_t)BSS * DSS;
static constexpr size_t OFS_AV    = OFS_Q  + (size_t)BSS * DSS;
static constexpr size_t OFS_TS    = OFS_AV + (size_t)BSS * DSS;    // thr state [DSS]
static constexpr size_t OFS_TO    = OFS_TS + DSS;                  // thr out [DMM]
static constexpr size_t OFS_TSUM  = OFS_TO + DMM;
static constexpr size_t OFS_TOSUM = OFS_TSUM + DSS;
static constexpr size_t OFS_FLAGS = OFS_TOSUM + DMM;               // int[96]
static constexpr size_t OFS_BAR   = OFS_FLAGS + 128;               // int[64]
static constexpr size_t WS_FLOATS = OFS_BAR + 64;                  // ~195.5 MiB

// ---------------- grid barrier (device-scope, sense-reversing) ----------------
__device__ __forceinline__ void gridbar(int* bar) {
  __syncthreads();
  if (threadIdx.x == 0) {
    __threadfence();                                  // release: wb L2, covers block's stores
    int* cnt = bar;
    int* gen = bar + 32;
    int g = __hip_atomic_load(gen, __ATOMIC_ACQUIRE, __HIP_MEMORY_SCOPE_AGENT);
    int a = __hip_atomic_fetch_add(cnt, 1, __ATOMIC_ACQ_REL, __HIP_MEMORY_SCOPE_AGENT);
    if (a == NBLK - 1) {
      __hip_atomic_store(cnt, 0, __ATOMIC_RELAXED, __HIP_MEMORY_SCOPE_AGENT);
      __hip_atomic_fetch_add(gen, 1, __ATOMIC_ACQ_REL, __HIP_MEMORY_SCOPE_AGENT);
    } else {
      while (__hip_atomic_load(gen, __ATOMIC_ACQUIRE, __HIP_MEMORY_SCOPE_AGENT) == g) {
        __builtin_amdgcn_s_sleep(1);
      }
    }
    __threadfence();                                  // acquire: invalidate L1/L2
  }
  __syncthreads();
}

// ---------------- LDS helpers (GEMM tiles, stride 260 = conflict-free b128) ----------------
__device__ __forceinline__ void stage_rows(float* __restrict__ dst, const float* __restrict__ src, int nrows) {
  int total = nrows * 64;                              // float4 count (256 floats/row)
  for (int i = threadIdx.x; i < total; i += NTHR) {
    int r = i >> 6, c4 = i & 63;
    float4 v = ((const float4*)(src + (size_t)r * DSS))[c4];
    ((float4*)(dst + r * 260))[c4] = v;
  }
}

__device__ __forceinline__ void tile_mm(const float* __restrict__ sA, const float* __restrict__ sB,
                                        float* o0, float* o1) {
  int r = threadIdx.x >> 4, c = threadIdx.x & 15;
  const float4* Ar = (const float4*)(sA + r * 260);
  const float4* B0 = (const float4*)(sB + c * 260);
  const float4* B1 = (const float4*)(sB + (c + 16) * 260);
  float a0 = 0.f, a1 = 0.f;
  #pragma unroll 8
  for (int k = 0; k < 64; ++k) {
    float4 a = Ar[k], b0 = B0[k], b1 = B1[k];
    a0 = fmaf(a.x, b0.x, a0); a0 = fmaf(a.y, b0.y, a0); a0 = fmaf(a.z, b0.z, a0); a0 = fmaf(a.w, b0.w, a0);
    a1 = fmaf(a.x, b1.x, a1); a1 = fmaf(a.y, b1.y, a1); a1 = fmaf(a.z, b1.z, a1); a1 = fmaf(a.w, b1.w, a1);
  }
  *o0 = a0; *o1 = a1;
}

__device__ __forceinline__ float dot256(const float* __restrict__ a, const float* __restrict__ b) {
  const float4* A4 = (const float4*)a; const float4* B4 = (const float4*)b;
  float s = 0.f;
  #pragma unroll 8
  for (int k = 0; k < 64; ++k) {
    float4 x = A4[k], y = B4[k];
    s = fmaf(x.x, y.x, s); s = fmaf(x.y, y.y, s); s = fmaf(x.z, y.z, s); s = fmaf(x.w, y.w, s);
  }
  return s;
}

// ---------------- flags: any(x_t > 0) ----------------
extern "C" __global__ void __launch_bounds__(256)
flags_kernel(const float* __restrict__ x, int* __restrict__ flags) {
  __shared__ int f;
  if (threadIdx.x == 0) f = 0;
  __syncthreads();
  int t = blockIdx.x;
  int any = 0;
  for (int b = 0; b < 4; ++b) {
    const float4* base = (const float4*)(x + ((size_t)(b * TT + t) * SSS) * DMM);
    for (int i = threadIdx.x; i < 16384; i += 256) {
      float4 v = base[i];
      any |= (v.x > 0.f) | (v.y > 0.f) | (v.z > 0.f) | (v.w > 0.f);
    }
  }
  if (any) atomicOr(&f, 1);
  __syncthreads();
  if (threadIdx.x == 0) flags[t] = f;
}

// ---------------- precompute: K = x Wk^T + bk, V = x Wv^T + bv, XD = x D^T ----------------
// virtual B matrix rows: [0,256)=Wk, [256,512)=Wv, [512,1024)=D ; all K=512.
extern "C" __global__ void __launch_bounds__(256)
pre_kernel(const float* __restrict__ x,
           const float* __restrict__ Wk, const float* __restrict__ bk,
           const float* __restrict__ Wv, const float* __restrict__ bv,
           const float* __restrict__ D,  float* __restrict__ ws) {
  __shared__ float As[32 * 68];   // [k][m], stride 68
  __shared__ float Bs[32 * 68];   // [k][n]
  int bid = blockIdx.x;
  int nt = bid & 15, mt = bid >> 4;          // 16 N-tiles, 768 M-tiles
  int row0 = mt * 64, col0 = nt * 64;
  int tid = threadIdx.x;
  int tr = tid & 15, tc = tid >> 4;
  float acc[4][4] = {};
  for (int kk = 0; kk < 512; kk += 32) {
    __syncthreads();
    { // stage A (x rows), transposed
      int m = tid >> 2, ks = (tid & 3) * 8;
      const float* src = x + (size_t)(row0 + m) * 512 + kk + ks;
      float4 a = *(const float4*)(src);
      float4 b = *(const float4*)(src + 4);
      As[(ks + 0) * 68 + m] = a.x; As[(ks + 1) * 68 + m] = a.y;
      As[(ks + 2) * 68 + m] = a.z; As[(ks + 3) * 68 + m] = a.w;
      As[(ks + 4) * 68 + m] = b.x; As[(ks + 5) * 68 + m] = b.y;
      As[(ks + 6) * 68 + m] = b.z; As[(ks + 7) * 68 + m] = b.w;
    }
    { // stage B (weight rows), transposed
      int n = tid >> 2, ks = (tid & 3) * 8;
      int gc = col0 + n;
      const float* wr = (gc < 256) ? (Wk + (size_t)gc * 512)
                      : (gc < 512) ? (Wv + (size_t)(gc - 256) * 512)
                                   : (D  + (size_t)(gc - 512) * 512);
      const float* src = wr + kk + ks;
      float4 a = *(const float4*)(src);
      float4 b = *(const float4*)(src + 4);
      Bs[(ks + 0) * 68 + n] = a.x; Bs[(ks + 1) * 68 + n] = a.y;
      Bs[(ks + 2) * 68 + n] = a.z; Bs[(ks + 3) * 68 + n] = a.w;
      Bs[(ks + 4) * 68 + n] = b.x; Bs[(ks + 5) * 68 + n] = b.y;
      Bs[(ks + 6) * 68 + n] = b.z; Bs[(ks + 7) * 68 + n] = b.w;
    }
    __syncthreads();
    #pragma unroll 8
    for (int k = 0; k < 32; ++k) {
      float4 a4 = *(const float4*)(As + k * 68 + tr * 4);
      float4 b4 = *(const float4*)(Bs + k * 68 + tc * 4);
      float am[4] = {a4.x, a4.y, a4.z, a4.w};
      float bn[4] = {b4.x, b4.y, b4.z, b4.w};
      #pragma unroll
      for (int i = 0; i < 4; ++i)
        #pragma unroll
        for (int j = 0; j < 4; ++j)
          acc[i][j] = fmaf(am[i], bn[j], acc[i][j]);
    }
  }
  // epilogue: remap rows (b,t,s) -> t*512 + b*128 + s, add bias, store
  for (int i = 0; i < 4; ++i) {
    int g = row0 + tr * 4 + i;
    int b = g / 12288, r1 = g % 12288;          // 12288 = 96*128
    int t_ = r1 / 128, s_ = r1 % 128;
    size_t drow = (size_t)t_ * BSS + b * SSS + s_;
    int gc0 = col0 + tc * 4;
    float4 o = make_float4(acc[i][0], acc[i][1], acc[i][2], acc[i][3]);
    if (gc0 < 256) {
      o.x += bk[gc0]; o.y += bk[gc0 + 1]; o.z += bk[gc0 + 2]; o.w += bk[gc0 + 3];
      *(float4*)(ws + OFS_K + drow * DSS + gc0) = o;
    } else if (gc0 < 512) {
      int c = gc0 - 256;
      o.x += bv[c]; o.y += bv[c + 1]; o.z += bv[c + 2]; o.w += bv[c + 3];
      *(float4*)(ws + OFS_V + drow * DSS + c) = o;
    } else {
      *(float4*)(ws + OFS_XD + drow * DMM + (gc0 - 512)) = o;
    }
  }
}

// ---------------- sequential recurrence (cooperative) ----------------
extern "C" __global__ void __launch_bounds__(NTHR, 1)
seq_kernel(const float* __restrict__ Aw, const float* __restrict__ Cw,
           const float* __restrict__ Wq, const float* __restrict__ bq,
           const float* __restrict__ Wo, const float* __restrict__ bo,
           float* __restrict__ ws, float* __restrict__ out) {
  extern __shared__ float sm[];
  float* sA   = sm;            // 8320 floats (32 rows x stride 260)
  float* sB   = sm + 8320;     // 8320
  float* csum = sm + 16640;    // 32
  // attention aliases (phase B only)
  float* qs  = sm;             // 512
  float* ss  = sm + 512;       // 4096 (scores/weights 8x512)
  float* kv  = sm + 4608;      // 64*76 = 4864 (K or V chunk)
  float* avp = sm + 9472;      // 2048 (split-K partials)

  float* Kbuf = ws + OFS_K;  float* Vbuf = ws + OFS_V;  float* XD = ws + OFS_XD;
  float* h  = ws + OFS_H;    float* sv = ws + OFS_SV;   float* ov = ws + OFS_OV;
  float* st = ws + OFS_ST;   float* qg = ws + OFS_Q;    float* av = ws + OFS_AV;
  float* ts = ws + OFS_TS;   float* to = ws + OFS_TO;
  float* tsum = ws + OFS_TSUM; float* tosum = ws + OFS_TOSUM;
  const int* flags = (const int*)(ws + OFS_FLAGS);
  int* bar = (int*)(ws + OFS_BAR);

  const int tid = threadIdx.x;
  const int bid = blockIdx.x;

  // ---- init state (ws is poisoned every call) ----
  {
    size_t g = (size_t)bid * NTHR + tid;
    for (size_t i = g; i < (size_t)524288; i += (size_t)NBLK * NTHR) h[i] = 0.f; // h,sv,ov contiguous
    if (g < DSS) { ts[g] = 1.f; tsum[g] = 0.f; }
    if (g < DMM) { to[g] = 1.f; tosum[g] = 0.f; }
  }
  gridbar(bar);

  for (int t = 0; t <= TT; ++t) {
    // ===== PHASE DA : D(t-1) on blocks 0..127  ||  A(t) on blocks 128..255 =====
    if (bid < 128) {
      if (t > 0) {
        int rt = bid >> 3, ct0 = (bid & 7) * 2;
        int r = rt * 32 + (tid >> 4), cl = tid & 15;
        int bI = r >> 7, sI = r & 127;
        size_t outbase = (((size_t)bI * TT + (t - 1)) * SSS + sI) * DMM;
        if (flags[t - 1]) {
          stage_rows(sA, h + (size_t)(rt * 32) * DSS, 32);
          const float* xdrow = XD + ((size_t)(t - 1) * BSS + r) * DMM;
          for (int cti = 0; cti < 2; ++cti) {
            int c0 = (ct0 + cti) * 32;
            __syncthreads();
            stage_rows(sB, Cw + (size_t)c0 * DSS, 32);
            if (tid < 32) csum[tid] = 0.f;
            __syncthreads();
            float a0, a1; tile_mm(sA, sB, &a0, &a1);
            int c_0 = c0 + cl, c_1 = c0 + cl + 16;
            float up0 = a0 + xdrow[c_0];
            float up1 = a1 + xdrow[c_1];
            float vp0 = ov[(size_t)r * DMM + c_0] * DECAYF + up0;
            float vp1 = ov[(size_t)r * DMM + c_1] * DECAYF + up1;
            float s0 = (vp0 >= to[c_0]) ? 1.f : 0.f;
            float s1 = (vp1 >= to[c_1]) ? 1.f : 0.f;
            ov[(size_t)r * DMM + c_0] = vp0 * (1.f - s0);
            ov[(size_t)r * DMM + c_1] = vp1 * (1.f - s1);
            out[outbase + c_0] = s0;
            out[outbase + c_1] = s1;
            atomicAdd(&csum[cl], s0);
            atomicAdd(&csum[cl + 16], s1);
            __syncthreads();
            if (tid < 32) atomicAdd(&tosum[c0 + tid], csum[tid]);
          }
        } else { // inactive step: output slice is zeros; ov/to untouched
          for (int cti = 0; cti < 2; ++cti) {
            int c0 = (ct0 + cti) * 32;
            out[outbase + c0 + cl] = 0.f;
            out[outbase + c0 + cl + 16] = 0.f;
          }
        }
      }
    } else {
      if (t < TT) {
        int a = bid - 128;
        int rt = a >> 3, ct = a & 7;
        int r = rt * 32 + (tid >> 4), cl = tid & 15;
        int c0 = ct * 32;
        stage_rows(sA, h + (size_t)(rt * 32) * DSS, 32);
        stage_rows(sB, Aw + (size_t)c0 * DSS, 32);
        __syncthreads();
        float a0, a1; tile_mm(sA, sB, &a0, &a1);
        st[(size_t)r * DSS + c0 + cl] = a0;
        st[(size_t)r * DSS + c0 + cl + 16] = a1;
        __syncthreads();
        stage_rows(sB, Wq + (size_t)c0 * DSS, 32);
        __syncthreads();
        tile_mm(sA, sB, &a0, &a1);
        qg[(size_t)r * DSS + c0 + cl] = a0 + bq[c0 + cl];
        qg[(size_t)r * DSS + c0 + cl + 16] = a1 + bq[c0 + cl + 16];
        if (a == 0 && t > 0 && tid < DSS) {   // LIF1 threshold adaptation (every step)
          ts[tid] += 0.1f * (tsum[tid] * (1.f / 512.f) - 0.1f);
          tsum[tid] = 0.f;
        }
      }
    }
    gridbar(bar);
    if (t == TT) break;

    // ===== PHASE B : attention (head, 8-query chunk) per block =====
    if (bid == 0 && t > 0 && flags[t - 1]) {  // LIF2 threshold adaptation (active steps only)
      if (tid < DMM) { to[tid] += 0.1f * (tosum[tid] * (1.f / 512.f) - 0.1f); tosum[tid] = 0.f; }
    }
    if (flags[t]) {
      int hd = bid >> 6, qc = bid & 63, q0 = qc * 8;
      const float* Kt = Kbuf + (size_t)t * BSS * DSS;
      const float* Vt = Vbuf + (size_t)t * BSS * DSS;
      { int i = tid >> 6, d = tid & 63;
        qs[i * 64 + d] = qg[(size_t)(q0 + i) * DSS + hd * 64 + d]; }
      __syncthreads();
      int sq = tid >> 6, sk = tid & 63;
      for (int ch = 0; ch < 8; ++ch) {        // scores, 64 keys/chunk
        for (int j = tid; j < 1024; j += NTHR) {
          int rr = j >> 4, c4 = j & 15;
          float4 v = *(const float4*)(Kt + (size_t)(ch * 64 + rr) * DSS + hd * 64 + c4 * 4);
          *(float4*)(kv + rr * 76 + c4 * 4) = v;
        }
        __syncthreads();
        const float4* qr = (const float4*)(qs + sq * 64);
        const float4* kr = (const float4*)(kv + sk * 76);
        float acc = 0.f;
        #pragma unroll
        for (int k4 = 0; k4 < 16; ++k4) {
          float4 qa = qr[k4], kb = kr[k4];
          acc = fmaf(qa.x, kb.x, acc); acc = fmaf(qa.y, kb.y, acc);
          acc = fmaf(qa.z, kb.z, acc); acc = fmaf(qa.w, kb.w, acc);
        }
        ss[sq * 512 + ch * 64 + sk] = acc * 0.125f;
        __syncthreads();
      }
      { // softmax: one wave per query row
        float* row = ss + sq * 512;
        float4 v0 = ((const float4*)row)[sk * 2];
        float4 v1 = ((const float4*)row)[sk * 2 + 1];
        float m = fmaxf(fmaxf(fmaxf(v0.x, v0.y), fmaxf(v0.z, v0.w)),
                        fmaxf(fmaxf(v1.x, v1.y), fmaxf(v1.z, v1.w)));
        for (int o = 32; o > 0; o >>= 1) m = fmaxf(m, __shfl_xor(m, o));
        v0.x = expf(v0.x - m); v0.y = expf(v0.y - m); v0.z = expf(v0.z - m); v0.w = expf(v0.w - m);
        v1.x = expf(v1.x - m); v1.y = expf(v1.y - m); v1.z = expf(v1.z - m); v1.w = expf(v1.w - m);
        float s = v0.x + v0.y + v0.z + v0.w + v1.x + v1.y + v1.z + v1.w;
        for (int o = 32; o > 0; o >>= 1) s += __shfl_xor(s, o);
        float inv = 1.f / s;
        v0.x *= inv; v0.y *= inv; v0.z *= inv; v0.w *= inv;
        v1.x *= inv; v1.y *= inv; v1.z *= inv; v1.w *= inv;
        ((float4*)row)[sk * 2] = v0; ((float4*)row)[sk * 2 + 1] = v1;
      }
      __syncthreads();
      // av = w @ V : split-K 4 groups, thread = (group, q, 4-wide d)
      int g = tid >> 7, qa_ = (tid >> 4) & 7, d4 = (tid & 15) * 4;
      float4 accv = make_float4(0.f, 0.f, 0.f, 0.f);
      for (int ch = 0; ch < 8; ++ch) {
        for (int j = tid; j < 1024; j += NTHR) {
          int rr = j >> 4, c4 = j & 15;
          float4 v = *(const float4*)(Vt + (size_t)(ch * 64 + rr) * DSS + hd * 64 + c4 * 4);
          *(float4*)(kv + rr * 76 + c4 * 4) = v;
        }
        __syncthreads();
        const float* wrow = ss + qa_ * 512 + ch * 64 + g * 16;
        #pragma unroll
        for (int kk = 0; kk < 16; kk += 4) {
          float4 w4 = *(const float4*)(wrow + kk);
          const float* vp0 = kv + (g * 16 + kk) * 76 + d4;
          float4 va = *(const float4*)(vp0);
          float4 vb = *(const float4*)(vp0 + 76);
          float4 vc = *(const float4*)(vp0 + 152);
          float4 vd = *(const float4*)(vp0 + 228);
          accv.x = fmaf(w4.x, va.x, accv.x); accv.y = fmaf(w4.x, va.y, accv.y);
          accv.z = fmaf(w4.x, va.z, accv.z); accv.w = fmaf(w4.x, va.w, accv.w);
          accv.x = fmaf(w4.y, vb.x, accv.x); accv.y = fmaf(w4.y, vb.y, accv.y);
          accv.z = fmaf(w4.y, vb.z, accv.z); accv.w = fmaf(w4.y, vb.w, accv.w);
          accv.x = fmaf(w4.z, vc.x, accv.x); accv.y = fmaf(w4.z, vc.y, accv.y);
          accv.z = fmaf(w4.z, vc.z, accv.z); accv.w = fmaf(w4.z, vc.w, accv.w);
          accv.x = fmaf(w4.w, vd.x, accv.x); accv.y = fmaf(w4.w, vd.y, accv.y);
          accv.z = fmaf(w4.w, vd.z, accv.z); accv.w = fmaf(w4.w, vd.w, accv.w);
        }
        __syncthreads();
      }
      *(float4*)(avp + (g * 8 + qa_) * 64 + d4) = accv;
      __syncthreads();
      { int qi = tid >> 6, d = tid & 63;
        float sum = avp[qi * 64 + d] + avp[512 + qi * 64 + d]
                  + avp[1024 + qi * 64 + d] + avp[1536 + qi * 64 + d];
        av[(size_t)(q0 + qi) * DSS + hd * 64 + d] = sum; }
    }
    gridbar(bar);

    // ===== PHASE C : gi = av Wo^T + bo ; LIF1 =====
    {
      int rt = bid >> 4, ct = bid & 15;
      int r = rt * 32 + (tid >> 4), cl = tid & 15;
      int c0 = ct * 16, c = c0 + cl;
      float gi = 0.f;
      if (flags[t]) {
        stage_rows(sA, av + (size_t)(rt * 32) * DSS, 32);
        stage_rows(sB, Wo + (size_t)c0 * DSS, 16);
        __syncthreads();
        gi = dot256(sA + (tid >> 4) * 260, sB + cl * 260) + bo[c];
      }
      if (tid < 16) csum[tid] = 0.f;
      __syncthreads();
      float in1 = st[(size_t)r * DSS + c] + gi;
      float vp = sv[(size_t)r * DSS + c] * DECAYF + in1;
      float sp = (vp >= ts[c]) ? 1.f : 0.f;
      h[(size_t)r * DSS + c] = sp;
      sv[(size_t)r * DSS + c] = vp * (1.f - sp);
      atomicAdd(&csum[cl], sp);
      __syncthreads();
      if (tid < 16) atomicAdd(&tsum[c0 + tid], csum[tid]);
    }
    gridbar(bar);
  }
}

// ---------------- host ----------------
extern "C" void kernel_launch(void* const* d_in, const int* in_sizes, int n_in,
                              void* d_out, int out_size, void* d_ws, size_t ws_size,
                              hipStream_t stream) {
  const float* x  = (const float*)d_in[0];
  const float* Aw = (const float*)d_in[1];
  const float* Cw = (const float*)d_in[2];
  const float* Dw = (const float*)d_in[3];
  const float* Wq = (const float*)d_in[4];
  const float* bq = (const float*)d_in[5];
  const float* Wk = (const float*)d_in[6];
  const float* bk = (const float*)d_in[7];
  const float* Wv = (const float*)d_in[8];
  const float* bv = (const float*)d_in[9];
  const float* Wo = (const float*)d_in[10];
  const float* bo = (const float*)d_in[11];
  float* ws  = (float*)d_ws;
  float* out = (float*)d_out;

  if (ws_size < WS_FLOATS * sizeof(float)) return;   // fail loudly (output stays poisoned)

  hipMemsetAsync((void*)(ws + OFS_BAR), 0, 256, stream);
  hipLaunchKernelGGL(flags_kernel, dim3(TT), dim3(256), 0, stream, x, (int*)(ws + OFS_FLAGS));
  hipLaunchKernelGGL(pre_kernel, dim3(12288), dim3(256), 0, stream, x, Wk, bk, Wv, bv, Dw, ws);

  hipFuncSetAttribute((const void*)seq_kernel, hipFuncAttributeMaxDynamicSharedMemorySize, SMEM_BYTES);
  void* kargs[] = { (void*)&Aw, (void*)&Cw, (void*)&Wq, (void*)&bq,
                    (void*)&Wo, (void*)&bo, (void*)&ws, (void*)&out };
  hipLaunchCooperativeKernel((void*)seq_kernel, dim3(NBLK), dim3(NTHR), kargs, SMEM_BYTES, stream);
}

// Round 3
// 10218.502 us; speedup vs baseline: 1.1677x; 1.1677x over previous
//
#include <hip/hip_runtime.h>
#include <math.h>

#define TT   96
#define SSS  128
#define DMM  512
#define DSS  256
#define BSS  512
#define NBLK 128
#define NTHR 1024
#define DECAYF 0.6065306597126334f
#define SMEM_BYTES 135712

// ---------------- workspace layout (float offsets) ----------------
static constexpr size_t OFS_K      = 0;                       // [96][512][256]
static constexpr size_t OFS_V      = 12582912;                // [96][512][256]
static constexpr size_t OFS_XD     = 25165824;                // [96][512][512]
static constexpr size_t OFS_AT     = 50331648;                // A^T  [256][256]
static constexpr size_t OFS_WQT    = 50397184;                // Wq^T [256][256]
static constexpr size_t OFS_WOT    = 50462720;                // Wo^T [256][256]
static constexpr size_t OFS_CT     = 50528256;                // C^T  [256][512]
static constexpr size_t OFS_TPART  = 50659328;                // [3][16][256]
static constexpr size_t OFS_TOPART = 50671616;                // [3][16][512]
static constexpr size_t OFS_FLAGS  = 50696192;                // int[96] (+pad)
static constexpr size_t OFS_BAR    = 50696320;                // int[64]
static constexpr size_t WS_FLOATS  = 50696384;                // 193.4 MiB < R1-proven 195.5 MiB

// ---------------- LDS layout (float offsets) ----------------
#define L_PART 0        /* 16640: scores part (4220) / AV part (16384) / gi part (4096) */
#define L_SW   16640    /* 8320 : scores [16 rows][520] */
#define L_SH   24960    /* 1024 : h spikes [4][256] */
#define L_SSV  25984    /* 1024 : sv */
#define L_SST  27008    /* 1024 : st */
#define L_SQV  28032    /* 1024 : q   (aliased: sou [4][512] = L_SQV..+2048) */
#define L_SAV  29056    /* 1024 : av */
#define L_SOV  30080    /* 2048 : ov [4][512] */
#define L_STS  32128    /* 256  : thr state */
#define L_STO  32384    /* 512  : thr out */
#define L_ACT  32896    /* 1024 ints: active-k lists [4][256] */
#define L_NACT 33920    /* 8 ints (index 7 = barrier-ok watchdog flag) */

// ---------------- grid barrier (sense-reversing, watchdog-bounded) ----------------
__device__ __forceinline__ void gridbar(int* bar, int* bok) {
  __syncthreads();
  if (threadIdx.x == 0) {
    if (*bok) {
      __threadfence();
      int* cnt = bar;
      int* gen = bar + 32;
      int g = __hip_atomic_load(gen, __ATOMIC_ACQUIRE, __HIP_MEMORY_SCOPE_AGENT);
      int a = __hip_atomic_fetch_add(cnt, 1, __ATOMIC_ACQ_REL, __HIP_MEMORY_SCOPE_AGENT);
      if (a == NBLK - 1) {
        __hip_atomic_store(cnt, 0, __ATOMIC_RELAXED, __HIP_MEMORY_SCOPE_AGENT);
        __hip_atomic_fetch_add(gen, 1, __ATOMIC_ACQ_REL, __HIP_MEMORY_SCOPE_AGENT);
      } else {
        int spin = 0;
        while (__hip_atomic_load(gen, __ATOMIC_ACQUIRE, __HIP_MEMORY_SCOPE_AGENT) == g) {
          __builtin_amdgcn_s_sleep(8);
          if (++spin > (1 << 22)) { *bok = 0; break; }   // ~0.5s: give up, never wedge GPU
        }
      }
      __threadfence();
    }
  }
  __syncthreads();
}

// ---------------- fallback: zero the output (keeps capture non-empty) ----------------
extern "C" __global__ void __launch_bounds__(256)
zfill_kernel(float* __restrict__ out, int n) {
  int i = blockIdx.x * 256 + threadIdx.x;
  if (i < n) out[i] = 0.f;
}

// ---------------- flags: any(x_t > 0) ----------------
extern "C" __global__ void __launch_bounds__(256)
flags_kernel(const float* __restrict__ x, int* __restrict__ flags) {
  __shared__ int f;
  if (threadIdx.x == 0) f = 0;
  __syncthreads();
  int t = blockIdx.x;
  int any = 0;
  for (int b = 0; b < 4; ++b) {
    const float4* base = (const float4*)(x + ((size_t)(b * TT + t) * SSS) * DMM);
    for (int i = threadIdx.x; i < 16384; i += 256) {
      float4 v = base[i];
      any |= (v.x > 0.f) | (v.y > 0.f) | (v.z > 0.f) | (v.w > 0.f);
    }
  }
  if (any) atomicOr(&f, 1);
  __syncthreads();
  if (threadIdx.x == 0) flags[t] = f;
}

// ---------------- weight transposes ----------------
extern "C" __global__ void __launch_bounds__(256)
tr_kernel(const float* __restrict__ A, const float* __restrict__ Wq,
          const float* __restrict__ Wo, const float* __restrict__ C,
          float* __restrict__ ws) {
  __shared__ float tile[32][33];
  int b = blockIdx.x;
  const float* src; float* dst; int RS, CS, tb;
  if (b < 64)       { src = A;  dst = ws + OFS_AT;  RS = 256; CS = 256; tb = b; }
  else if (b < 128) { src = Wq; dst = ws + OFS_WQT; RS = 256; CS = 256; tb = b - 64; }
  else if (b < 192) { src = Wo; dst = ws + OFS_WOT; RS = 256; CS = 256; tb = b - 128; }
  else              { src = C;  dst = ws + OFS_CT;  RS = 512; CS = 256; tb = b - 192; }
  int tpr = CS / 32;
  int trr = tb / tpr, tcc = tb % tpr;
  int r0 = trr * 32, c0 = tcc * 32;
  int tx = threadIdx.x & 31, ty = threadIdx.x >> 5;
  #pragma unroll
  for (int j = 0; j < 4; ++j)
    tile[ty + j * 8][tx] = src[(size_t)(r0 + ty + j * 8) * CS + c0 + tx];
  __syncthreads();
  #pragma unroll
  for (int j = 0; j < 4; ++j)
    dst[(size_t)(c0 + ty + j * 8) * RS + r0 + tx] = tile[tx][ty + j * 8];
}

// ---------------- precompute K, V, XD (proven in R1) ----------------
extern "C" __global__ void __launch_bounds__(256)
pre_kernel(const float* __restrict__ x,
           const float* __restrict__ Wk, const float* __restrict__ bk,
           const float* __restrict__ Wv, const float* __restrict__ bv,
           const float* __restrict__ D,  float* __restrict__ ws) {
  __shared__ float As[32 * 68];
  __shared__ float Bs[32 * 68];
  int bid = blockIdx.x;
  int nt = bid & 15, mt = bid >> 4;
  int row0 = mt * 64, col0 = nt * 64;
  int tid = threadIdx.x;
  int trd = tid & 15, tc = tid >> 4;
  float acc[4][4] = {};
  for (int kk = 0; kk < 512; kk += 32) {
    __syncthreads();
    { int m = tid >> 2, ks = (tid & 3) * 8;
      const float* src = x + (size_t)(row0 + m) * 512 + kk + ks;
      float4 a = *(const float4*)(src);
      float4 b = *(const float4*)(src + 4);
      As[(ks + 0) * 68 + m] = a.x; As[(ks + 1) * 68 + m] = a.y;
      As[(ks + 2) * 68 + m] = a.z; As[(ks + 3) * 68 + m] = a.w;
      As[(ks + 4) * 68 + m] = b.x; As[(ks + 5) * 68 + m] = b.y;
      As[(ks + 6) * 68 + m] = b.z; As[(ks + 7) * 68 + m] = b.w; }
    { int n = tid >> 2, ks = (tid & 3) * 8;
      int gc = col0 + n;
      const float* wr = (gc < 256) ? (Wk + (size_t)gc * 512)
                      : (gc < 512) ? (Wv + (size_t)(gc - 256) * 512)
                                   : (D  + (size_t)(gc - 512) * 512);
      const float* src = wr + kk + ks;
      float4 a = *(const float4*)(src);
      float4 b = *(const float4*)(src + 4);
      Bs[(ks + 0) * 68 + n] = a.x; Bs[(ks + 1) * 68 + n] = a.y;
      Bs[(ks + 2) * 68 + n] = a.z; Bs[(ks + 3) * 68 + n] = a.w;
      Bs[(ks + 4) * 68 + n] = b.x; Bs[(ks + 5) * 68 + n] = b.y;
      Bs[(ks + 6) * 68 + n] = b.z; Bs[(ks + 7) * 68 + n] = b.w; }
    __syncthreads();
    #pragma unroll 8
    for (int k = 0; k < 32; ++k) {
      float4 a4 = *(const float4*)(As + k * 68 + trd * 4);
      float4 b4 = *(const float4*)(Bs + k * 68 + tc * 4);
      float am[4] = {a4.x, a4.y, a4.z, a4.w};
      float bn[4] = {b4.x, b4.y, b4.z, b4.w};
      #pragma unroll
      for (int i = 0; i < 4; ++i)
        #pragma unroll
        for (int j = 0; j < 4; ++j)
          acc[i][j] = fmaf(am[i], bn[j], acc[i][j]);
    }
  }
  for (int i = 0; i < 4; ++i) {
    int g = row0 + trd * 4 + i;
    int b = g / 12288, r1 = g % 12288;
    int t_ = r1 / 128, s_ = r1 % 128;
    size_t drow = (size_t)t_ * BSS + b * SSS + s_;
    int gc0 = col0 + tc * 4;
    float4 o = make_float4(acc[i][0], acc[i][1], acc[i][2], acc[i][3]);
    if (gc0 < 256) {
      o.x += bk[gc0]; o.y += bk[gc0 + 1]; o.z += bk[gc0 + 2]; o.w += bk[gc0 + 3];
      *(float4*)(ws + OFS_K + drow * DSS + gc0) = o;
    } else if (gc0 < 512) {
      int c = gc0 - 256;
      o.x += bv[c]; o.y += bv[c + 1]; o.z += bv[c + 2]; o.w += bv[c + 3];
      *(float4*)(ws + OFS_V + drow * DSS + c) = o;
    } else {
      *(float4*)(ws + OFS_XD + drow * DMM + (gc0 - 512)) = o;
    }
  }
}

// ---------------- sequential recurrence: row-local, 1 barrier/step ----------------
extern "C" __global__ void __launch_bounds__(NTHR, 4)
seq_kernel(const float* __restrict__ bq, const float* __restrict__ bo,
           float* __restrict__ ws, float* __restrict__ out) {
  extern __shared__ float sm[];
  float* part = sm + L_PART;
  float* sw   = sm + L_SW;
  float* sh   = sm + L_SH;
  float* ssv  = sm + L_SSV;
  float* sst  = sm + L_SST;
  float* sqv  = sm + L_SQV;
  float* sav  = sm + L_SAV;
  float* sou  = sm + L_SQV;      // alias over sqv+sav (2048 floats)
  float* sov  = sm + L_SOV;
  float* sts  = sm + L_STS;
  float* sto  = sm + L_STO;
  int*   acts = (int*)(sm + L_ACT);
  int*   nact = (int*)(sm + L_NACT);
  int*   bok  = nact + 7;

  const float* At  = ws + OFS_AT;
  const float* Wqt = ws + OFS_WQT;
  const float* Wot = ws + OFS_WOT;
  const float* Ct  = ws + OFS_CT;
  const float* XD  = ws + OFS_XD;
  float* tpart  = ws + OFS_TPART;
  float* topart = ws + OFS_TOPART;
  const int* flags = (const int*)(ws + OFS_FLAGS);
  int* bar = (int*)(ws + OFS_BAR);

  const int tid = threadIdx.x;
  const int bid = blockIdx.x;

  // ---- init (ws/LDS poisoned every call) ----
  sh[tid] = 0.f;                  // NTHR==1024 covers each 1024-float buffer
  ssv[tid] = 0.f;
  sov[tid] = 0.f; sov[1024 + tid] = 0.f;
  if (tid < 256) sts[tid] = 1.f;
  if (tid < 512) sto[tid] = 1.f;
  if (tid == 0) *bok = 1;
  { size_t g0 = (size_t)bid * NTHR + tid;
    for (size_t i = g0; i < (size_t)36864; i += (size_t)NBLK * NTHR)
      tpart[i] = 0.f; }           // tpart[3][16][256] + topart[3][16][512] contiguous
  gridbar(bar, bok);

  for (int t = 0; t < TT; ++t) {
    const int fl = flags[t];
    const int tb3 = t % 3;
    const float* Kt = ws + OFS_K + (size_t)t * BSS * DSS;
    const float* Vt = ws + OFS_V + (size_t)t * BSS * DSS;

    // ===== P1: active-k compaction of h (ascending order => exact vs dense) =====
    if (tid < 256) {
      int r = tid >> 6, lane = tid & 63;
      int base = 0;
      for (int seg = 0; seg < 4; ++seg) {
        int k = seg * 64 + lane;
        bool p = sh[r * 256 + k] > 0.5f;
        unsigned long long m = __ballot(p);
        int pre = __popcll(m & ((1ull << lane) - 1ull));
        if (p) acts[r * 256 + base + pre] = k;
        base += __popcll(m);
      }
      if (lane == 0) nact[r] = base;
    }
    __syncthreads();

    // ===== P2: st = h@A^T (sparse gather) ; q = h@Wq^T + bq =====
    {
      int r = tid >> 8, c = tid & 255;
      int n = nact[r];
      const int* al = acts + r * 256;
      float aS = 0.f, aQ = 0.f;
      if (fl) {
        for (int i = 0; i < n; ++i) {
          int k = al[i];
          aS += At[(size_t)k * 256 + c];
          aQ += Wqt[(size_t)k * 256 + c];
        }
        sqv[r * 256 + c] = aQ + bq[c];
      } else {
        for (int i = 0; i < n; ++i) aS += At[(size_t)(al[i]) * 256 + c];
      }
      sst[r * 256 + c] = aS;
    }
    __syncthreads();

    if (fl) {
      // ===== P3: scores (16 rounds x 32 keys; K from global, L2-resident, coalesced) =====
      int kl = tid >> 5, dsg = tid & 31;
      float4 qa[4], qb[4];
      #pragma unroll
      for (int r = 0; r < 4; ++r) {
        qa[r] = *(const float4*)(sqv + r * 256 + dsg * 8);
        qb[r] = *(const float4*)(sqv + r * 256 + dsg * 8 + 4);
      }
      for (int kb = 0; kb < 16; ++kb) {
        int key = kb * 32 + kl;
        const float4* kp = (const float4*)(Kt + (size_t)key * 256 + dsg * 8);
        float4 k0 = kp[0], k1 = kp[1];
        float p[4];
        #pragma unroll
        for (int r = 0; r < 4; ++r) {
          float s = 0.f;
          s = fmaf(k0.x, qa[r].x, s); s = fmaf(k0.y, qa[r].y, s);
          s = fmaf(k0.z, qa[r].z, s); s = fmaf(k0.w, qa[r].w, s);
          s = fmaf(k1.x, qb[r].x, s); s = fmaf(k1.y, qb[r].y, s);
          s = fmaf(k1.z, qb[r].z, s); s = fmaf(k1.w, qb[r].w, s);
          p[r] = s;
        }
        *(float4*)(part + (size_t)(kl * 33 + dsg) * 4) = make_float4(p[0], p[1], p[2], p[3]);
        __syncthreads();
        if (tid < 512) {
          int r2 = tid >> 7, hd = (tid >> 5) & 3, kl2 = tid & 31;
          float s = 0.f;
          #pragma unroll
          for (int d8 = 0; d8 < 8; ++d8)
            s += part[(size_t)(kl2 * 33 + hd * 8 + d8) * 4 + r2];
          sw[(r2 * 4 + hd) * 520 + kb * 32 + kl2] = s * 0.125f;
        }
        __syncthreads();
      }

      // ===== P4: softmax (one wave per (r,hd) row of 512) =====
      {
        int w = tid >> 6, lane = tid & 63;
        float* row = sw + w * 520;
        float4 v0 = ((const float4*)row)[lane * 2];
        float4 v1 = ((const float4*)row)[lane * 2 + 1];
        float m = fmaxf(fmaxf(fmaxf(v0.x, v0.y), fmaxf(v0.z, v0.w)),
                        fmaxf(fmaxf(v1.x, v1.y), fmaxf(v1.z, v1.w)));
        for (int o = 32; o > 0; o >>= 1) m = fmaxf(m, __shfl_xor(m, o));
        v0.x = expf(v0.x - m); v0.y = expf(v0.y - m); v0.z = expf(v0.z - m); v0.w = expf(v0.w - m);
        v1.x = expf(v1.x - m); v1.y = expf(v1.y - m); v1.z = expf(v1.z - m); v1.w = expf(v1.w - m);
        float s = v0.x + v0.y + v0.z + v0.w + v1.x + v1.y + v1.z + v1.w;
        for (int o = 32; o > 0; o >>= 1) s += __shfl_xor(s, o);
        float inv = 1.f / s;
        v0.x *= inv; v0.y *= inv; v0.z *= inv; v0.w *= inv;
        v1.x *= inv; v1.y *= inv; v1.z *= inv; v1.w *= inv;
        ((float4*)row)[lane * 2] = v0; ((float4*)row)[lane * 2 + 1] = v1;
      }
      __syncthreads();

      // ===== P5: AV (V from global, coalesced; 16-way key split) =====
      {
        int kg = tid >> 6, dq = tid & 63;
        int hd = dq >> 4;
        float4 acc[4];
        #pragma unroll
        for (int r = 0; r < 4; ++r) acc[r] = make_float4(0.f, 0.f, 0.f, 0.f);
        for (int kb = 0; kb < 8; ++kb) {
          #pragma unroll
          for (int i = 0; i < 4; ++i) {
            int key = kb * 64 + kg * 4 + i;
            float4 v = *(const float4*)(Vt + (size_t)key * 256 + dq * 4);
            #pragma unroll
            for (int r = 0; r < 4; ++r) {
              float wv = sw[(r * 4 + hd) * 520 + key];
              acc[r].x = fmaf(wv, v.x, acc[r].x);
              acc[r].y = fmaf(wv, v.y, acc[r].y);
              acc[r].z = fmaf(wv, v.z, acc[r].z);
              acc[r].w = fmaf(wv, v.w, acc[r].w);
            }
          }
        }
        #pragma unroll
        for (int r = 0; r < 4; ++r)
          *(float4*)(part + (size_t)((kg * 4 + r) * 64 + dq) * 4) = acc[r];
      }
      __syncthreads();
      {
        int row = tid >> 8, dd = tid & 255;
        float s = 0.f;
        #pragma unroll
        for (int kg = 0; kg < 16; ++kg)
          s += part[(size_t)kg * 1024 + row * 256 + dd];
        sav[row * 256 + dd] = s;
      }
      __syncthreads();
    }

    // ===== P6: gi = av@Wo^T + bo ; LIF1 ; tpart =====
    {
      int r = tid >> 8, c = tid & 255;
      float gi = 0.f;
      if (fl) {
        int ks4 = (tid >> 6) & 3, cq = tid & 63;
        float4 a = make_float4(0.f, 0.f, 0.f, 0.f);
        const float* avr = sav + r * 256;
        for (int k = ks4 * 64; k < ks4 * 64 + 64; ++k) {
          float avv = avr[k];
          float4 wo = *(const float4*)(Wot + (size_t)k * 256 + cq * 4);
          a.x = fmaf(avv, wo.x, a.x); a.y = fmaf(avv, wo.y, a.y);
          a.z = fmaf(avv, wo.z, a.z); a.w = fmaf(avv, wo.w, a.w);
        }
        *(float4*)(part + (size_t)((r * 4 + ks4) * 64 + cq) * 4) = a;
        __syncthreads();
        gi = (((part[(size_t)(r * 4 + 0) * 256 + c]
              + part[(size_t)(r * 4 + 1) * 256 + c])
              + part[(size_t)(r * 4 + 2) * 256 + c])
              + part[(size_t)(r * 4 + 3) * 256 + c]) + bo[c];
      }
      float in1 = sst[r * 256 + c] + gi;
      float vp = ssv[r * 256 + c] * DECAYF + in1;
      float sp = (vp >= sts[c]) ? 1.f : 0.f;
      ssv[r * 256 + c] = vp * (1.f - sp);
      sh[r * 256 + c] = sp;
    }
    __syncthreads();
    if (tid < 256) {
      float s = sh[tid] + sh[256 + tid] + sh[512 + tid] + sh[768 + tid];
      atomicAdd(tpart + ((size_t)tb3 * 16 + (bid & 15)) * 256 + tid, s);
    }

    // ===== P7: up = h2@C^T + XD ; LIF2 ; out ; topart =====
    if (fl) {
      if (tid < 256) {
        int r = tid >> 6, lane = tid & 63;
        int base = 0;
        for (int seg = 0; seg < 4; ++seg) {
          int k = seg * 64 + lane;
          bool p = sh[r * 256 + k] > 0.5f;
          unsigned long long m = __ballot(p);
          int pre = __popcll(m & ((1ull << lane) - 1ull));
          if (p) acts[r * 256 + base + pre] = k;
          base += __popcll(m);
        }
        if (lane == 0) nact[r] = base;
      }
      __syncthreads();
      {
        int r = tid >> 8, c2 = tid & 255, m0 = c2 * 2;
        int grow = bid * 4 + r;
        int n = nact[r];
        const int* al = acts + r * 256;
        float a0 = 0.f, a1 = 0.f;
        for (int i = 0; i < n; ++i) {
          int k = al[i];
          float2 cv = *(const float2*)(Ct + (size_t)k * 512 + m0);
          a0 += cv.x; a1 += cv.y;
        }
        float2 xd = *(const float2*)(XD + ((size_t)t * 512 + grow) * 512 + m0);
        float up0 = a0 + xd.x, up1 = a1 + xd.y;
        float vp0 = sov[r * 512 + m0] * DECAYF + up0;
        float vp1 = sov[r * 512 + m0 + 1] * DECAYF + up1;
        float s0 = (vp0 >= sto[m0]) ? 1.f : 0.f;
        float s1 = (vp1 >= sto[m0 + 1]) ? 1.f : 0.f;
        sov[r * 512 + m0] = vp0 * (1.f - s0);
        sov[r * 512 + m0 + 1] = vp1 * (1.f - s1);
        sou[r * 512 + m0] = s0; sou[r * 512 + m0 + 1] = s1;
        int b = grow >> 7, sI = grow & 127;
        float2 o2; o2.x = s0; o2.y = s1;
        *(float2*)(out + (((size_t)b * TT + t) * SSS + sI) * DMM + m0) = o2;
      }
      __syncthreads();
      if (tid < 512) {
        float s = sou[tid] + sou[512 + tid] + sou[1024 + tid] + sou[1536 + tid];
        atomicAdd(topart + ((size_t)tb3 * 16 + (bid & 15)) * 512 + tid, s);
      }
    } else {
      int r = tid >> 8, c2 = tid & 255, m0 = c2 * 2;
      int grow = bid * 4 + r;
      int b = grow >> 7, sI = grow & 127;
      float2 z; z.x = 0.f; z.y = 0.f;
      *(float2*)(out + (((size_t)b * TT + t) * SSS + sI) * DMM + m0) = z;
    }

    gridbar(bar, bok);

    // ===== P8: threshold adaptation (exact replicated reduce) + rotate-zero =====
    if (tid < 256) {
      float s = 0.f;
      const float* tp = tpart + (size_t)tb3 * 4096;
      #pragma unroll
      for (int b2 = 0; b2 < 16; ++b2) s += tp[b2 * 256 + tid];
      sts[tid] += 0.1f * (s * (1.f / 512.f) - 0.1f);
    } else if (tid >= 512 && fl) {
      int c = tid - 512;
      const float* tp = topart + (size_t)tb3 * 8192;
      float s = 0.f;
      #pragma unroll
      for (int b2 = 0; b2 < 16; ++b2) s += tp[b2 * 512 + c];
      sto[c] += 0.1f * (s * (1.f / 512.f) - 0.1f);
    }
    {  // zero buffer (t+2)%3: all readers of it finished before gridbar#t (two-barrier gap)
      int bz = (t + 2) % 3;
      size_t g = (size_t)bid * NTHR + tid;
      if (g < 4096) tpart[(size_t)bz * 4096 + g] = 0.f;
      else if (g < 12288) topart[(size_t)bz * 8192 + (g - 4096)] = 0.f;
    }
    __syncthreads();
  }
}

// ---------------- host ----------------
extern "C" void kernel_launch(void* const* d_in, const int* in_sizes, int n_in,
                              void* d_out, int out_size, void* d_ws, size_t ws_size,
                              hipStream_t stream) {
  const float* x  = (const float*)d_in[0];
  const float* Aw = (const float*)d_in[1];
  const float* Cw = (const float*)d_in[2];
  const float* Dw = (const float*)d_in[3];
  const float* Wq = (const float*)d_in[4];
  const float* bq = (const float*)d_in[5];
  const float* Wk = (const float*)d_in[6];
  const float* bk = (const float*)d_in[7];
  const float* Wv = (const float*)d_in[8];
  const float* bv = (const float*)d_in[9];
  const float* Wo = (const float*)d_in[10];
  const float* bo = (const float*)d_in[11];
  float* ws  = (float*)d_ws;
  float* out = (float*)d_out;

  if (ws_size < WS_FLOATS * sizeof(float)) {
    // not enough scratch: emit a defined (wrong) output; never an empty capture
    hipLaunchKernelGGL(zfill_kernel, dim3((out_size + 255) / 256), dim3(256), 0, stream,
                       out, out_size);
    return;
  }

  hipMemsetAsync((void*)(ws + OFS_BAR), 0, 256, stream);
  hipLaunchKernelGGL(flags_kernel, dim3(TT), dim3(256), 0, stream, x, (int*)(ws + OFS_FLAGS));
  hipLaunchKernelGGL(tr_kernel, dim3(320), dim3(256), 0, stream, Aw, Wq, Wo, Cw, ws);
  hipLaunchKernelGGL(pre_kernel, dim3(12288), dim3(256), 0, stream, x, Wk, bk, Wv, bv, Dw, ws);

  hipFuncSetAttribute((const void*)seq_kernel, hipFuncAttributeMaxDynamicSharedMemorySize, SMEM_BYTES);
  void* kargs[] = { (void*)&bq, (void*)&bo, (void*)&ws, (void*)&out };
  hipLaunchCooperativeKernel((void*)seq_kernel, dim3(NBLK), dim3(NTHR), kargs, SMEM_BYTES, stream);
}

// Round 4
// 8982.373 us; speedup vs baseline: 1.3284x; 1.1376x over previous
//
#include <hip/hip_runtime.h>
#include <math.h>

#define TT   96
#define SSS  128
#define DMM  512
#define DSS  256
#define BSS  512
#define NBLK 128
#define NTHR 1024
#define DECAYF 0.6065306597126334f
#define SMEM_BYTES 135712

#define AT_ADD(p, v) __hip_atomic_fetch_add((p), (v), __ATOMIC_RELAXED, __HIP_MEMORY_SCOPE_AGENT)
#define AT_ST(p, v)  __hip_atomic_store((p), (v), __ATOMIC_RELAXED, __HIP_MEMORY_SCOPE_AGENT)
#define AT_LD(p)     __hip_atomic_load((p), __ATOMIC_RELAXED, __HIP_MEMORY_SCOPE_AGENT)

// ---------------- workspace layout (float offsets) ----------------
static constexpr size_t OFS_K      = 0;                       // [96][512][256]
static constexpr size_t OFS_V      = 12582912;                // [96][512][256]
static constexpr size_t OFS_XD     = 25165824;                // [96][512][512]
static constexpr size_t OFS_AT     = 50331648;                // A^T  [256][256]
static constexpr size_t OFS_WQT    = 50397184;                // Wq^T [256][256]
static constexpr size_t OFS_WOT    = 50462720;                // Wo^T [256][256]
static constexpr size_t OFS_CT     = 50528256;                // C^T  [256][512]
static constexpr size_t OFS_TPART  = 50659328;                // [3][16][256]
static constexpr size_t OFS_TOPART = 50671616;                // [3][16][512]
static constexpr size_t OFS_FLAGS  = 50696192;                // int[96] (+pad)
static constexpr size_t OFS_BAR    = 50696320;                // int[64]
static constexpr size_t WS_FLOATS  = 50696384;                // 193.4 MiB

// ---------------- LDS layout (float offsets) ----------------
#define L_PART 0        /* 16640: AV part (16384) / gi part (4096) */
#define L_SW   16640    /* 8320 : scores [16 rows][520] */
#define L_SH   24960    /* 1024 : h spikes [4][256] */
#define L_SSV  25984    /* 1024 : sv */
#define L_SST  27008    /* 1024 : st */
#define L_SQV  28032    /* 1024 : q   (aliased: sou [4][512] = L_SQV..+2048) */
#define L_SAV  29056    /* 1024 : av */
#define L_SOV  30080    /* 2048 : ov [4][512] */
#define L_STS  32128    /* 256  : thr state */
#define L_STO  32384    /* 512  : thr out */
#define L_ACT  32896    /* 1024 ints: active-k lists [4][256] */
#define L_NACT 33920    /* 8 ints (index 7 = barrier-ok watchdog flag) */

// ---------------- grid barrier (fence-free: agent atomics only, no L2 inv) ----------------
__device__ __forceinline__ void gridbar(int* bar, int* bok) {
  __syncthreads();             // compiler drains vmcnt before s_barrier (all threads' atomics ack'd)
  if (threadIdx.x == 0 && *bok) {
    asm volatile("s_waitcnt vmcnt(0)" ::: "memory");
    int* cnt = bar;
    int* gen = bar + 32;
    int g = AT_LD(gen);
    int a = AT_ADD(cnt, 1);
    if (a == NBLK - 1) {
      AT_ST(cnt, 0);
      AT_ADD(gen, 1);
    } else {
      int spin = 0;
      while (AT_LD(gen) == g) {
        __builtin_amdgcn_s_sleep(2);
        if (++spin > (1 << 23)) { *bok = 0; break; }   // never wedge the GPU
      }
    }
    __atomic_signal_fence(__ATOMIC_SEQ_CST);           // compiler-only ordering
  }
  __syncthreads();
}

// ---------------- fallback: zero the output (keeps capture non-empty) ----------------
extern "C" __global__ void __launch_bounds__(256)
zfill_kernel(float* __restrict__ out, int n) {
  int i = blockIdx.x * 256 + threadIdx.x;
  if (i < n) out[i] = 0.f;
}

// ---------------- flags: any(x_t > 0) ----------------
extern "C" __global__ void __launch_bounds__(256)
flags_kernel(const float* __restrict__ x, int* __restrict__ flags) {
  __shared__ int f;
  if (threadIdx.x == 0) f = 0;
  __syncthreads();
  int t = blockIdx.x;
  int any = 0;
  for (int b = 0; b < 4; ++b) {
    const float4* base = (const float4*)(x + ((size_t)(b * TT + t) * SSS) * DMM);
    for (int i = threadIdx.x; i < 16384; i += 256) {
      float4 v = base[i];
      any |= (v.x > 0.f) | (v.y > 0.f) | (v.z > 0.f) | (v.w > 0.f);
    }
  }
  if (any) atomicOr(&f, 1);
  __syncthreads();
  if (threadIdx.x == 0) flags[t] = f;
}

// ---------------- weight transposes ----------------
extern "C" __global__ void __launch_bounds__(256)
tr_kernel(const float* __restrict__ A, const float* __restrict__ Wq,
          const float* __restrict__ Wo, const float* __restrict__ C,
          float* __restrict__ ws) {
  __shared__ float tile[32][33];
  int b = blockIdx.x;
  const float* src; float* dst; int RS, CS, tb;
  if (b < 64)       { src = A;  dst = ws + OFS_AT;  RS = 256; CS = 256; tb = b; }
  else if (b < 128) { src = Wq; dst = ws + OFS_WQT; RS = 256; CS = 256; tb = b - 64; }
  else if (b < 192) { src = Wo; dst = ws + OFS_WOT; RS = 256; CS = 256; tb = b - 128; }
  else              { src = C;  dst = ws + OFS_CT;  RS = 512; CS = 256; tb = b - 192; }
  int tpr = CS / 32;
  int trr = tb / tpr, tcc = tb % tpr;
  int r0 = trr * 32, c0 = tcc * 32;
  int tx = threadIdx.x & 31, ty = threadIdx.x >> 5;
  #pragma unroll
  for (int j = 0; j < 4; ++j)
    tile[ty + j * 8][tx] = src[(size_t)(r0 + ty + j * 8) * CS + c0 + tx];
  __syncthreads();
  #pragma unroll
  for (int j = 0; j < 4; ++j)
    dst[(size_t)(c0 + ty + j * 8) * RS + r0 + tx] = tile[tx][ty + j * 8];
}

// ---------------- precompute K, V, XD (proven in R1/R3) ----------------
extern "C" __global__ void __launch_bounds__(256)
pre_kernel(const float* __restrict__ x,
           const float* __restrict__ Wk, const float* __restrict__ bk,
           const float* __restrict__ Wv, const float* __restrict__ bv,
           const float* __restrict__ D,  float* __restrict__ ws) {
  __shared__ float As[32 * 68];
  __shared__ float Bs[32 * 68];
  int bid = blockIdx.x;
  int nt = bid & 15, mt = bid >> 4;
  int row0 = mt * 64, col0 = nt * 64;
  int tid = threadIdx.x;
  int trd = tid & 15, tc = tid >> 4;
  float acc[4][4] = {};
  for (int kk = 0; kk < 512; kk += 32) {
    __syncthreads();
    { int m = tid >> 2, ks = (tid & 3) * 8;
      const float* src = x + (size_t)(row0 + m) * 512 + kk + ks;
      float4 a = *(const float4*)(src);
      float4 b = *(const float4*)(src + 4);
      As[(ks + 0) * 68 + m] = a.x; As[(ks + 1) * 68 + m] = a.y;
      As[(ks + 2) * 68 + m] = a.z; As[(ks + 3) * 68 + m] = a.w;
      As[(ks + 4) * 68 + m] = b.x; As[(ks + 5) * 68 + m] = b.y;
      As[(ks + 6) * 68 + m] = b.z; As[(ks + 7) * 68 + m] = b.w; }
    { int n = tid >> 2, ks = (tid & 3) * 8;
      int gc = col0 + n;
      const float* wr = (gc < 256) ? (Wk + (size_t)gc * 512)
                      : (gc < 512) ? (Wv + (size_t)(gc - 256) * 512)
                                   : (D  + (size_t)(gc - 512) * 512);
      const float* src = wr + kk + ks;
      float4 a = *(const float4*)(src);
      float4 b = *(const float4*)(src + 4);
      Bs[(ks + 0) * 68 + n] = a.x; Bs[(ks + 1) * 68 + n] = a.y;
      Bs[(ks + 2) * 68 + n] = a.z; Bs[(ks + 3) * 68 + n] = a.w;
      Bs[(ks + 4) * 68 + n] = b.x; Bs[(ks + 5) * 68 + n] = b.y;
      Bs[(ks + 6) * 68 + n] = b.z; Bs[(ks + 7) * 68 + n] = b.w; }
    __syncthreads();
    #pragma unroll 8
    for (int k = 0; k < 32; ++k) {
      float4 a4 = *(const float4*)(As + k * 68 + trd * 4);
      float4 b4 = *(const float4*)(Bs + k * 68 + tc * 4);
      float am[4] = {a4.x, a4.y, a4.z, a4.w};
      float bn[4] = {b4.x, b4.y, b4.z, b4.w};
      #pragma unroll
      for (int i = 0; i < 4; ++i)
        #pragma unroll
        for (int j = 0; j < 4; ++j)
          acc[i][j] = fmaf(am[i], bn[j], acc[i][j]);
    }
  }
  for (int i = 0; i < 4; ++i) {
    int g = row0 + trd * 4 + i;
    int b = g / 12288, r1 = g % 12288;
    int t_ = r1 / 128, s_ = r1 % 128;
    size_t drow = (size_t)t_ * BSS + b * SSS + s_;
    int gc0 = col0 + tc * 4;
    float4 o = make_float4(acc[i][0], acc[i][1], acc[i][2], acc[i][3]);
    if (gc0 < 256) {
      o.x += bk[gc0]; o.y += bk[gc0 + 1]; o.z += bk[gc0 + 2]; o.w += bk[gc0 + 3];
      *(float4*)(ws + OFS_K + drow * DSS + gc0) = o;
    } else if (gc0 < 512) {
      int c = gc0 - 256;
      o.x += bv[c]; o.y += bv[c + 1]; o.z += bv[c + 2]; o.w += bv[c + 3];
      *(float4*)(ws + OFS_V + drow * DSS + c) = o;
    } else {
      *(float4*)(ws + OFS_XD + drow * DMM + (gc0 - 512)) = o;
    }
  }
}

// ---------------- sequential recurrence: row-local, 1 barrier/step, L2 stays warm ----------------
extern "C" __global__ void __launch_bounds__(NTHR, 4)
seq_kernel(const float* __restrict__ bq, const float* __restrict__ bo,
           float* __restrict__ ws, float* __restrict__ out) {
  extern __shared__ float sm[];
  float* part = sm + L_PART;
  float* sw   = sm + L_SW;
  float* sh   = sm + L_SH;
  float* ssv  = sm + L_SSV;
  float* sst  = sm + L_SST;
  float* sqv  = sm + L_SQV;
  float* sav  = sm + L_SAV;
  float* sou  = sm + L_SQV;      // alias over sqv+sav (2048 floats)
  float* sov  = sm + L_SOV;
  float* sts  = sm + L_STS;
  float* sto  = sm + L_STO;
  int*   acts = (int*)(sm + L_ACT);
  int*   nact = (int*)(sm + L_NACT);
  int*   bok  = nact + 7;

  const float* At  = ws + OFS_AT;
  const float* Wqt = ws + OFS_WQT;
  const float* Wot = ws + OFS_WOT;
  const float* Ct  = ws + OFS_CT;
  const float* XD  = ws + OFS_XD;
  float* tpart  = ws + OFS_TPART;
  float* topart = ws + OFS_TOPART;
  const int* flags = (const int*)(ws + OFS_FLAGS);
  int* bar = (int*)(ws + OFS_BAR);

  const int tid = threadIdx.x;
  const int bid = blockIdx.x;

  // ---- init (ws/LDS poisoned every call) ----
  sh[tid] = 0.f;
  ssv[tid] = 0.f;
  sov[tid] = 0.f; sov[1024 + tid] = 0.f;
  if (tid < 256) sts[tid] = 1.f;
  if (tid < 512) sto[tid] = 1.f;
  if (tid == 0) *bok = 1;
  { size_t g0 = (size_t)bid * NTHR + tid;
    for (size_t i = g0; i < (size_t)36864; i += (size_t)NBLK * NTHR)
      AT_ST(&tpart[i], 0.f); }   // tpart[3][16][256] + topart[3][16][512] contiguous
  gridbar(bar, bok);

  for (int t = 0; t < TT; ++t) {
    const int fl = flags[t];
    const int tb3 = t % 3;
    const float* Kt = ws + OFS_K + (size_t)t * BSS * DSS;
    const float* Vt = ws + OFS_V + (size_t)t * BSS * DSS;

    // ===== P1: active-k compaction of h (ascending order => exact vs dense) =====
    if (tid < 256) {
      int r = tid >> 6, lane = tid & 63;
      int base = 0;
      for (int seg = 0; seg < 4; ++seg) {
        int k = seg * 64 + lane;
        bool p = sh[r * 256 + k] > 0.5f;
        unsigned long long m = __ballot(p);
        int pre = __popcll(m & ((1ull << lane) - 1ull));
        if (p) acts[r * 256 + base + pre] = k;
        base += __popcll(m);
      }
      if (lane == 0) nact[r] = base;
    }
    __syncthreads();

    // ===== P2: st = h@A^T (sparse gather, L2-hot) ; q = h@Wq^T + bq =====
    {
      int r = tid >> 8, c = tid & 255;
      int n = nact[r];
      const int* al = acts + r * 256;
      float aS = 0.f, aQ = 0.f;
      if (fl) {
        for (int i = 0; i < n; ++i) {
          int k = al[i];
          aS += At[(size_t)k * 256 + c];
          aQ += Wqt[(size_t)k * 256 + c];
        }
        sqv[r * 256 + c] = aQ + bq[c];
      } else {
        for (int i = 0; i < n; ++i) aS += At[(size_t)(al[i]) * 256 + c];
      }
      sst[r * 256 + c] = aS;
    }
    __syncthreads();

    if (fl) {
      // ===== P3: scores — barrier-free. thread=(head-pair, key); q broadcast from LDS =====
      {
        int hp  = tid >> 9;                 // 0/1 -> heads {2hp, 2hp+1}
        int key = tid & 511;
        const float4* kp = (const float4*)(Kt + (size_t)key * 256 + hp * 128);
        float a0[4] = {0.f, 0.f, 0.f, 0.f};
        float a1[4] = {0.f, 0.f, 0.f, 0.f};
        int db = hp * 128;
        #pragma unroll 4
        for (int i = 0; i < 16; ++i) {
          float4 kv4 = kp[i];
          #pragma unroll
          for (int r = 0; r < 4; ++r) {
            float4 q4 = *(const float4*)(sqv + r * 256 + db + i * 4);
            a0[r] = fmaf(kv4.x, q4.x, a0[r]);
            a0[r] = fmaf(kv4.y, q4.y, a0[r]);
            a0[r] = fmaf(kv4.z, q4.z, a0[r]);
            a0[r] = fmaf(kv4.w, q4.w, a0[r]);
          }
        }
        #pragma unroll 4
        for (int i = 16; i < 32; ++i) {
          float4 kv4 = kp[i];
          #pragma unroll
          for (int r = 0; r < 4; ++r) {
            float4 q4 = *(const float4*)(sqv + r * 256 + db + i * 4);
            a1[r] = fmaf(kv4.x, q4.x, a1[r]);
            a1[r] = fmaf(kv4.y, q4.y, a1[r]);
            a1[r] = fmaf(kv4.z, q4.z, a1[r]);
            a1[r] = fmaf(kv4.w, q4.w, a1[r]);
          }
        }
        int hd0 = hp * 2;
        #pragma unroll
        for (int r = 0; r < 4; ++r) {
          sw[(r * 4 + hd0) * 520 + key]     = a0[r] * 0.125f;
          sw[(r * 4 + hd0 + 1) * 520 + key] = a1[r] * 0.125f;
        }
      }
      __syncthreads();

      // ===== P4: softmax (one wave per (r,hd) row of 512) =====
      {
        int w = tid >> 6, lane = tid & 63;
        float* row = sw + w * 520;
        float4 v0 = ((const float4*)row)[lane * 2];
        float4 v1 = ((const float4*)row)[lane * 2 + 1];
        float m = fmaxf(fmaxf(fmaxf(v0.x, v0.y), fmaxf(v0.z, v0.w)),
                        fmaxf(fmaxf(v1.x, v1.y), fmaxf(v1.z, v1.w)));
        for (int o = 32; o > 0; o >>= 1) m = fmaxf(m, __shfl_xor(m, o));
        v0.x = expf(v0.x - m); v0.y = expf(v0.y - m); v0.z = expf(v0.z - m); v0.w = expf(v0.w - m);
        v1.x = expf(v1.x - m); v1.y = expf(v1.y - m); v1.z = expf(v1.z - m); v1.w = expf(v1.w - m);
        float s = v0.x + v0.y + v0.z + v0.w + v1.x + v1.y + v1.z + v1.w;
        for (int o = 32; o > 0; o >>= 1) s += __shfl_xor(s, o);
        float inv = 1.f / s;
        v0.x *= inv; v0.y *= inv; v0.z *= inv; v0.w *= inv;
        v1.x *= inv; v1.y *= inv; v1.z *= inv; v1.w *= inv;
        ((float4*)row)[lane * 2] = v0; ((float4*)row)[lane * 2 + 1] = v1;
      }
      __syncthreads();

      // ===== P5: AV (V from global, coalesced, L2-hot; 16-way key split) =====
      {
        int kg = tid >> 6, dq = tid & 63;
        int hd = dq >> 4;
        float4 acc[4];
        #pragma unroll
        for (int r = 0; r < 4; ++r) acc[r] = make_float4(0.f, 0.f, 0.f, 0.f);
        for (int kb = 0; kb < 8; ++kb) {
          #pragma unroll
          for (int i = 0; i < 4; ++i) {
            int key = kb * 64 + kg * 4 + i;
            float4 v = *(const float4*)(Vt + (size_t)key * 256 + dq * 4);
            #pragma unroll
            for (int r = 0; r < 4; ++r) {
              float wv = sw[(r * 4 + hd) * 520 + key];
              acc[r].x = fmaf(wv, v.x, acc[r].x);
              acc[r].y = fmaf(wv, v.y, acc[r].y);
              acc[r].z = fmaf(wv, v.z, acc[r].z);
              acc[r].w = fmaf(wv, v.w, acc[r].w);
            }
          }
        }
        #pragma unroll
        for (int r = 0; r < 4; ++r)
          *(float4*)(part + (size_t)((kg * 4 + r) * 64 + dq) * 4) = acc[r];
      }
      __syncthreads();
      {
        int row = tid >> 8, dd = tid & 255;
        float s = 0.f;
        #pragma unroll
        for (int kg = 0; kg < 16; ++kg)
          s += part[(size_t)kg * 1024 + row * 256 + dd];
        sav[row * 256 + dd] = s;
      }
      __syncthreads();
    }

    // ===== P6: gi = av@Wo^T + bo ; LIF1 ; tpart =====
    {
      int r = tid >> 8, c = tid & 255;
      float gi = 0.f;
      if (fl) {
        int ks4 = (tid >> 6) & 3, cq = tid & 63;
        float4 a = make_float4(0.f, 0.f, 0.f, 0.f);
        const float* avr = sav + r * 256;
        for (int k = ks4 * 64; k < ks4 * 64 + 64; ++k) {
          float avv = avr[k];
          float4 wo = *(const float4*)(Wot + (size_t)k * 256 + cq * 4);
          a.x = fmaf(avv, wo.x, a.x); a.y = fmaf(avv, wo.y, a.y);
          a.z = fmaf(avv, wo.z, a.z); a.w = fmaf(avv, wo.w, a.w);
        }
        *(float4*)(part + (size_t)((r * 4 + ks4) * 64 + cq) * 4) = a;
        __syncthreads();
        gi = (((part[(size_t)(r * 4 + 0) * 256 + c]
              + part[(size_t)(r * 4 + 1) * 256 + c])
              + part[(size_t)(r * 4 + 2) * 256 + c])
              + part[(size_t)(r * 4 + 3) * 256 + c]) + bo[c];
      }
      float in1 = sst[r * 256 + c] + gi;
      float vp = ssv[r * 256 + c] * DECAYF + in1;
      float sp = (vp >= sts[c]) ? 1.f : 0.f;
      ssv[r * 256 + c] = vp * (1.f - sp);
      sh[r * 256 + c] = sp;
    }
    __syncthreads();
    if (tid < 256) {
      float s = sh[tid] + sh[256 + tid] + sh[512 + tid] + sh[768 + tid];
      AT_ADD(tpart + ((size_t)tb3 * 16 + (bid & 15)) * 256 + tid, s);
    }

    // ===== P7: up = h2@C^T + XD ; LIF2 ; out ; topart =====
    if (fl) {
      if (tid < 256) {
        int r = tid >> 6, lane = tid & 63;
        int base = 0;
        for (int seg = 0; seg < 4; ++seg) {
          int k = seg * 64 + lane;
          bool p = sh[r * 256 + k] > 0.5f;
          unsigned long long m = __ballot(p);
          int pre = __popcll(m & ((1ull << lane) - 1ull));
          if (p) acts[r * 256 + base + pre] = k;
          base += __popcll(m);
        }
        if (lane == 0) nact[r] = base;
      }
      __syncthreads();
      {
        int r = tid >> 8, c2 = tid & 255, m0 = c2 * 2;
        int grow = bid * 4 + r;
        int n = nact[r];
        const int* al = acts + r * 256;
        float a0 = 0.f, a1 = 0.f;
        for (int i = 0; i < n; ++i) {
          int k = al[i];
          float2 cv = *(const float2*)(Ct + (size_t)k * 512 + m0);
          a0 += cv.x; a1 += cv.y;
        }
        float2 xd = *(const float2*)(XD + ((size_t)t * 512 + grow) * 512 + m0);
        float up0 = a0 + xd.x, up1 = a1 + xd.y;
        float vp0 = sov[r * 512 + m0] * DECAYF + up0;
        float vp1 = sov[r * 512 + m0 + 1] * DECAYF + up1;
        float s0 = (vp0 >= sto[m0]) ? 1.f : 0.f;
        float s1 = (vp1 >= sto[m0 + 1]) ? 1.f : 0.f;
        sov[r * 512 + m0] = vp0 * (1.f - s0);
        sov[r * 512 + m0 + 1] = vp1 * (1.f - s1);
        sou[r * 512 + m0] = s0; sou[r * 512 + m0 + 1] = s1;
        int b = grow >> 7, sI = grow & 127;
        float2 o2; o2.x = s0; o2.y = s1;
        *(float2*)(out + (((size_t)b * TT + t) * SSS + sI) * DMM + m0) = o2;
      }
      __syncthreads();
      if (tid < 512) {
        float s = sou[tid] + sou[512 + tid] + sou[1024 + tid] + sou[1536 + tid];
        AT_ADD(topart + ((size_t)tb3 * 16 + (bid & 15)) * 512 + tid, s);
      }
    } else {
      int r = tid >> 8, c2 = tid & 255, m0 = c2 * 2;
      int grow = bid * 4 + r;
      int b = grow >> 7, sI = grow & 127;
      float2 z; z.x = 0.f; z.y = 0.f;
      *(float2*)(out + (((size_t)b * TT + t) * SSS + sI) * DMM + m0) = z;
    }

    gridbar(bar, bok);

    // ===== P8: threshold adaptation (coherence-point reads; exact integer sums) =====
    if (tid < 256) {
      const float* tp = tpart + (size_t)tb3 * 4096 + tid;
      float s = 0.f;
      #pragma unroll
      for (int b2 = 0; b2 < 16; ++b2) s += AT_LD(tp + b2 * 256);
      sts[tid] += 0.1f * (s * (1.f / 512.f) - 0.1f);
    } else if (tid >= 512 && fl) {
      int c = tid - 512;
      const float* tp = topart + (size_t)tb3 * 8192 + c;
      float s = 0.f;
      #pragma unroll
      for (int b2 = 0; b2 < 16; ++b2) s += AT_LD(tp + b2 * 512);
      sto[c] += 0.1f * (s * (1.f / 512.f) - 0.1f);
    }
    {  // zero buffer (t+2)%3 (atomic stores -> coherence point; 2-barrier gap before reuse)
      int bz = (t + 2) % 3;
      size_t g = (size_t)bid * NTHR + tid;
      if (g < 4096) AT_ST(&tpart[(size_t)bz * 4096 + g], 0.f);
      else if (g < 12288) AT_ST(&topart[(size_t)bz * 8192 + (g - 4096)], 0.f);
    }
    __syncthreads();
  }
}

// ---------------- host ----------------
extern "C" void kernel_launch(void* const* d_in, const int* in_sizes, int n_in,
                              void* d_out, int out_size, void* d_ws, size_t ws_size,
                              hipStream_t stream) {
  const float* x  = (const float*)d_in[0];
  const float* Aw = (const float*)d_in[1];
  const float* Cw = (const float*)d_in[2];
  const float* Dw = (const float*)d_in[3];
  const float* Wq = (const float*)d_in[4];
  const float* bq = (const float*)d_in[5];
  const float* Wk = (const float*)d_in[6];
  const float* bk = (const float*)d_in[7];
  const float* Wv = (const float*)d_in[8];
  const float* bv = (const float*)d_in[9];
  const float* Wo = (const float*)d_in[10];
  const float* bo = (const float*)d_in[11];
  float* ws  = (float*)d_ws;
  float* out = (float*)d_out;

  if (ws_size < WS_FLOATS * sizeof(float)) {
    hipLaunchKernelGGL(zfill_kernel, dim3((out_size + 255) / 256), dim3(256), 0, stream,
                       out, out_size);
    return;
  }

  hipMemsetAsync((void*)(ws + OFS_BAR), 0, 256, stream);
  hipLaunchKernelGGL(flags_kernel, dim3(TT), dim3(256), 0, stream, x, (int*)(ws + OFS_FLAGS));
  hipLaunchKernelGGL(tr_kernel, dim3(320), dim3(256), 0, stream, Aw, Wq, Wo, Cw, ws);
  hipLaunchKernelGGL(pre_kernel, dim3(12288), dim3(256), 0, stream, x, Wk, bk, Wv, bv, Dw, ws);

  hipFuncSetAttribute((const void*)seq_kernel, hipFuncAttributeMaxDynamicSharedMemorySize, SMEM_BYTES);
  void* kargs[] = { (void*)&bq, (void*)&bo, (void*)&ws, (void*)&out };
  hipLaunchCooperativeKernel((void*)seq_kernel, dim3(NBLK), dim3(NTHR), kargs, SMEM_BYTES, stream);
}